// Round 3
// baseline (317.452 us; speedup 1.0000x reference)
//
#include <hip/hip_runtime.h>
#include <hip/hip_bf16.h>

constexpr int B = 8, C = 128, H = 80, W = 80, O = 128;
constexpr int HW = H * W;              // 6400
constexpr int NPIX = B * HW;           // 51200
constexpr int KC = C * 9;              // 1152
constexpr int TP = 16;                 // pixels per block (main kernel)
constexpr int SSTB = KC + 8;           // LDS row stride in bf16 (2320 B: +4 banks/row)

typedef __attribute__((ext_vector_type(8))) short short8;
typedef __attribute__((ext_vector_type(4))) float f32x4;

__device__ inline ushort f2b(float f) {  // fp32 -> bf16 bits, RNE
  uint u = __float_as_uint(f);
  return (ushort)((u + 0x7FFFu + ((u >> 16) & 1u)) >> 16);
}
__device__ inline void unp(uint u, float& lo, float& hi) {  // 2 packed bf16 -> fp32
  lo = __uint_as_float(u << 16);
  hi = __uint_as_float(u & 0xFFFF0000u);
}

// ------- kernel 0a: x [B][C][HW] fp32 -> xt [B][HW][C] bf16 -----------------
__global__ __launch_bounds__(256) void k_xt(const float* __restrict__ x,
                                            ushort* __restrict__ xt) {
  const int t = threadIdx.x;
  const int g = t >> 4;            // channel chunk: c = 8g..8g+7
  const int hl = t & 15;
  const int p0 = blockIdx.x * 16;
  const int b = p0 / HW, hw = p0 - b * HW + hl;
  const float* xb = x + (size_t)b * C * HW + hw;
  uint u[4];
#pragma unroll
  for (int i = 0; i < 4; ++i) {
    float lo = xb[(size_t)(g * 8 + 2 * i) * HW];
    float hi = xb[(size_t)(g * 8 + 2 * i + 1) * HW];
    u[i] = (uint)f2b(lo) | ((uint)f2b(hi) << 16);
  }
  *(uint4*)(xt + ((size_t)b * HW + hw) * C + g * 8) = make_uint4(u[0], u[1], u[2], u[3]);
}

// ------- kernel 0b: w_dcn [O][C][9] fp32 -> wt [O][9*128] bf16 (k-major) ----
__global__ __launch_bounds__(256) void k_wt(const float* __restrict__ w_dcn,
                                            ushort* __restrict__ wt) {
  int i = blockIdx.x * 256 + threadIdx.x;  // flat = o*1152 + k*128 + c
  if (i >= O * KC) return;
  int c = i & 127, k = (i >> 7) % 9, o = i / KC;
  wt[i] = f2b(w_dcn[(size_t)o * KC + c * 9 + k]);
}

// ------- kernel 1: offset conv (C=128 -> 27, 3x3, pad 1) --------------------
// block = 64 pixels x 4 waves; wave wv handles channels [32wv, 32wv+32)
// (wave-uniform c => weights stay scalar-loaded); LDS reduce across waves.
__global__ __launch_bounds__(256) void k_offconv2(
    const float* __restrict__ x, const float* __restrict__ w_off,
    const float* __restrict__ b_off, float* __restrict__ om) {
  __shared__ float s_acc[27][64];
  const int t = threadIdx.x;
  const int px = t & 63;
  const int wv = __builtin_amdgcn_readfirstlane(t >> 6);
  const int p = blockIdx.x * 64 + px;
  const int b = p / HW, hw = p - b * HW;
  const int h = hw / W, w = hw - (hw / W) * W;
  float acc[27];
#pragma unroll
  for (int oc = 0; oc < 27; ++oc) acc[oc] = 0.0f;
  const float* xb = x + ((size_t)b * C + wv * 32) * HW;
  for (int c = 0; c < 32; ++c) {
    float xv[9];
#pragma unroll
    for (int ky = 0; ky < 3; ++ky) {
      int y = h + ky - 1;
#pragma unroll
      for (int kx = 0; kx < 3; ++kx) {
        int xx = w + kx - 1;
        bool ok = ((unsigned)y < (unsigned)H) && ((unsigned)xx < (unsigned)W);
        xv[ky * 3 + kx] = ok ? xb[(size_t)c * HW + y * W + xx] : 0.0f;
      }
    }
#pragma unroll
    for (int oc = 0; oc < 27; ++oc) {
      const float* wo = w_off + ((size_t)oc * C + wv * 32 + c) * 9;
#pragma unroll
      for (int i = 0; i < 9; ++i) acc[oc] = fmaf(xv[i], wo[i], acc[oc]);
    }
  }
  // staged cross-wave reduction
  for (int pass = 0; pass < 4; ++pass) {
    if (wv == pass) {
      if (pass == 0) {
#pragma unroll
        for (int oc = 0; oc < 27; ++oc) s_acc[oc][px] = acc[oc];
      } else {
#pragma unroll
        for (int oc = 0; oc < 27; ++oc) s_acc[oc][px] += acc[oc];
      }
    }
    __syncthreads();
  }
  const int hwb = (blockIdx.x * 64) - b * HW;
  for (int i = t; i < 27 * 64; i += 256) {
    int oc = i >> 6, pxx = i & 63;
    om[((size_t)b * 27 + oc) * HW + hwb + pxx] = s_acc[oc][pxx] + b_off[oc];
  }
}

// ------- kernel 2: bilinear gather (bf16, NHWC) + MFMA GEMM ----------------
// block: 256 threads (4 waves), TP=16 pixels, all O=128 outputs.
__global__ __launch_bounds__(256, 3) void k_dcn2(
    const ushort* __restrict__ xt, const float* __restrict__ om,
    const ushort* __restrict__ wt, float* __restrict__ outr) {
  __shared__ float s_w[TP][9][4];
  __shared__ int s_i[TP][9][4];
  __shared__ __align__(16) ushort s_a[TP * SSTB];   // sampled[pix][k*128+c] bf16
  const int t = threadIdx.x;
  const int p0 = blockIdx.x * TP;
  const int b = p0 / HW, hw0 = p0 - b * HW;

  // phase 1: bilinear metadata (mask folded into corner weights)
  if (t < TP * 9) {
    int px = t / 9, k = t - (t / 9) * 9;
    int hw = hw0 + px, h = hw / W, w = hw - (hw / W) * W;
    int ky = k / 3, kx = k - ky * 3;
    const float* omp = om + (size_t)b * 27 * HW + hw;
    float dy = omp[(size_t)(2 * k) * HW];
    float dx = omp[(size_t)(2 * k + 1) * HW];
    float mk = 1.0f / (1.0f + __expf(-omp[(size_t)(18 + k) * HW]));
    float py = dy + (float)(h - 1 + ky);
    float pxf = dx + (float)(w - 1 + kx);
    float y0f = floorf(py), x0f = floorf(pxf);
    float wy1 = py - y0f, wx1 = pxf - x0f;
    float wy0 = 1.0f - wy1, wx0 = 1.0f - wx1;
    int y0 = (int)y0f, x0 = (int)x0f;
    int y1 = y0 + 1, x1 = x0 + 1;
    bool vy0 = (y0 >= 0) && (y0 < H);
    bool vy1 = (y1 >= 0) && (y1 < H);
    bool vx0 = (x0 >= 0) && (x0 < W);
    bool vx1 = (x1 >= 0) && (x1 < W);
    int cy0 = min(max(y0, 0), H - 1), cy1 = min(max(y1, 0), H - 1);
    int cx0 = min(max(x0, 0), W - 1), cx1 = min(max(x1, 0), W - 1);
    s_w[px][k][0] = (vy0 && vx0) ? wy0 * wx0 * mk : 0.0f;
    s_w[px][k][1] = (vy0 && vx1) ? wy0 * wx1 * mk : 0.0f;
    s_w[px][k][2] = (vy1 && vx0) ? wy1 * wx0 * mk : 0.0f;
    s_w[px][k][3] = (vy1 && vx1) ? wy1 * wx1 * mk : 0.0f;
    s_i[px][k][0] = cy0 * W + cx0;
    s_i[px][k][1] = cy0 * W + cx1;
    s_i[px][k][2] = cy1 * W + cx0;
    s_i[px][k][3] = cy1 * W + cx1;
  }
  __syncthreads();

  // phase 2: gather -> LDS bf16.  thread = (pixel g, channel-chunk j)
  {
    const int g = t >> 4;
    const int j = t & 15;
    const int co = j * 8;
    const ushort* xb = xt + (size_t)b * HW * C + co;
    ushort* sa = s_a + g * SSTB + co;
#pragma unroll
    for (int k = 0; k < 9; ++k) {
      float w0 = s_w[g][k][0], w1 = s_w[g][k][1];
      float w2 = s_w[g][k][2], w3 = s_w[g][k][3];
      uint4 u0 = *(const uint4*)(xb + (size_t)s_i[g][k][0] * C);
      uint4 u1 = *(const uint4*)(xb + (size_t)s_i[g][k][1] * C);
      uint4 u2 = *(const uint4*)(xb + (size_t)s_i[g][k][2] * C);
      uint4 u3 = *(const uint4*)(xb + (size_t)s_i[g][k][3] * C);
      uint q0[4] = {u0.x, u0.y, u0.z, u0.w};
      uint q1[4] = {u1.x, u1.y, u1.z, u1.w};
      uint q2[4] = {u2.x, u2.y, u2.z, u2.w};
      uint q3[4] = {u3.x, u3.y, u3.z, u3.w};
      uint r[4];
#pragma unroll
      for (int e = 0; e < 4; ++e) {
        float a0, a1, b0, b1, c0, c1, d0, d1;
        unp(q0[e], a0, a1);
        unp(q1[e], b0, b1);
        unp(q2[e], c0, c1);
        unp(q3[e], d0, d1);
        float vlo = fmaf(w3, d0, fmaf(w2, c0, fmaf(w1, b0, w0 * a0)));
        float vhi = fmaf(w3, d1, fmaf(w2, c1, fmaf(w1, b1, w0 * a1)));
        r[e] = (uint)f2b(vlo) | ((uint)f2b(vhi) << 16);
      }
      *(uint4*)(sa + k * C) = make_uint4(r[0], r[1], r[2], r[3]);
    }
  }
  __syncthreads();

  // phase 3: D = Wt (M=128 o) x sampled (N=16 pix), K=1152
  {
    const int lane = t & 63, wv = t >> 6;
    const int rl = lane & 15, gh = lane >> 4;
    const ushort* a0p = wt + (size_t)(wv * 32 + rl) * KC + 8 * gh;
    const ushort* a1p = a0p + 16 * KC;
    const ushort* bp = s_a + rl * SSTB + 8 * gh;
    f32x4 acc0 = {0.f, 0.f, 0.f, 0.f}, acc1 = {0.f, 0.f, 0.f, 0.f};
#pragma unroll 4
    for (int kk = 0; kk < KC; kk += 32) {
      short8 av0 = *(const short8*)(a0p + kk);
      short8 av1 = *(const short8*)(a1p + kk);
      short8 bv = *(const short8*)(bp + kk);
      acc0 = __builtin_amdgcn_mfma_f32_16x16x32_bf16(av0, bv, acc0, 0, 0, 0);
      acc1 = __builtin_amdgcn_mfma_f32_16x16x32_bf16(av1, bv, acc1, 0, 0, 0);
    }
    // D: col(pix) = lane&15, row(m) = 4*(lane>>4)+r
    float* outb = outr + (size_t)b * O * HW + hw0 + rl;
#pragma unroll
    for (int r = 0; r < 4; ++r) {
      outb[(size_t)(wv * 32 + 4 * gh + r) * HW] = acc0[r];
      outb[(size_t)(wv * 32 + 16 + 4 * gh + r) * HW] = acc1[r];
    }
  }
}

// ------- kernel 3: BN stats (one block per output channel) ------------------
__global__ __launch_bounds__(1024) void k_bnstats(const float* __restrict__ outr,
                                                  float* __restrict__ stats) {
  const int o = blockIdx.x;
  float s = 0.f, s2 = 0.f;
  for (int e4 = threadIdx.x; e4 < B * HW / 4; e4 += 1024) {
    int b = e4 / (HW / 4), hw4 = e4 - b * (HW / 4);
    float4 v = ((const float4*)(outr + ((size_t)b * O + o) * HW))[hw4];
    s += v.x + v.y + v.z + v.w;
    s2 = fmaf(v.x, v.x, s2);
    s2 = fmaf(v.y, v.y, s2);
    s2 = fmaf(v.z, v.z, s2);
    s2 = fmaf(v.w, v.w, s2);
  }
#pragma unroll
  for (int off = 32; off > 0; off >>= 1) {
    s += __shfl_down(s, off);
    s2 += __shfl_down(s2, off);
  }
  __shared__ float rs[16], rs2[16];
  int wid = threadIdx.x >> 6, lane = threadIdx.x & 63;
  if (lane == 0) { rs[wid] = s; rs2[wid] = s2; }
  __syncthreads();
  if (threadIdx.x == 0) {
    float S = 0.f, S2 = 0.f;
#pragma unroll
    for (int i = 0; i < 16; ++i) { S += rs[i]; S2 += rs2[i]; }
    const float inv = 1.0f / (float)(B * HW);
    float mu = S * inv;
    float var = S2 * inv - mu * mu;
    stats[2 * o] = mu;
    stats[2 * o + 1] = rsqrtf(var + 1e-5f);
  }
}

// ------- kernel 4: BN affine + SiLU, in place on d_out ----------------------
__global__ __launch_bounds__(256) void k_bnapply(
    float* __restrict__ outr, const float* __restrict__ stats,
    const float* __restrict__ gamma, const float* __restrict__ beta) {
  const int n4 = B * O * HW / 4;
  for (int i = blockIdx.x * blockDim.x + threadIdx.x; i < n4;
       i += gridDim.x * blockDim.x) {
    int o = (i / (HW / 4)) % O;
    float a = stats[2 * o + 1] * gamma[o];
    float bb = fmaf(-stats[2 * o], a, beta[o]);
    float4 v = ((const float4*)outr)[i];
    float y0 = fmaf(v.x, a, bb);
    float y1 = fmaf(v.y, a, bb);
    float y2 = fmaf(v.z, a, bb);
    float y3 = fmaf(v.w, a, bb);
    v.x = y0 / (1.0f + __expf(-y0));
    v.y = y1 / (1.0f + __expf(-y1));
    v.z = y2 / (1.0f + __expf(-y2));
    v.w = y3 / (1.0f + __expf(-y3));
    ((float4*)outr)[i] = v;
  }
}

extern "C" void kernel_launch(void* const* d_in, const int* in_sizes, int n_in,
                              void* d_out, int out_size, void* d_ws, size_t ws_size,
                              hipStream_t stream) {
  const float* x = (const float*)d_in[0];
  const float* w_dcn = (const float*)d_in[1];
  // d_in[2] = b_dcn: per-channel constant, exactly cancelled by BN mean-sub.
  const float* w_off = (const float*)d_in[3];
  const float* b_off = (const float*)d_in[4];
  const float* gamma = (const float*)d_in[5];
  const float* beta = (const float*)d_in[6];
  float* out = (float*)d_out;
  // workspace: om 5.53MB | stats 1KB | xt 13.1MB | wt 0.29MB  (~18.9MB total)
  float* om = (float*)d_ws;
  float* stats = om + (size_t)B * 27 * HW;
  ushort* xt = (ushort*)(stats + 256);
  ushort* wt = xt + (size_t)B * HW * C;

  k_xt<<<NPIX / 16, 256, 0, stream>>>(x, xt);
  k_wt<<<(O * KC + 255) / 256, 256, 0, stream>>>(w_dcn, wt);
  k_offconv2<<<NPIX / 64, 256, 0, stream>>>(x, w_off, b_off, om);
  k_dcn2<<<NPIX / TP, 256, 0, stream>>>(xt, om, wt, out);
  k_bnstats<<<O, 1024, 0, stream>>>(out, stats);
  k_bnapply<<<2048, 256, 0, stream>>>(out, stats, gamma, beta);
}

// Round 5
// 211.870 us; speedup vs baseline: 1.4983x; 1.4983x over previous
//
#include <hip/hip_runtime.h>
#include <hip/hip_bf16.h>

constexpr int B = 8, C = 128, H = 80, W = 80, O = 128;
constexpr int HW = H * W;              // 6400
constexpr int NPIX = B * HW;           // 51200
constexpr int KC = C * 9;              // 1152
constexpr int PX = 64;                 // pixels per block (dcn/offc kernels)

typedef __attribute__((ext_vector_type(8))) short short8;
typedef __attribute__((ext_vector_type(4))) float f32x4;

__device__ inline ushort f2b(float f) {  // fp32 -> bf16 bits, RNE
  uint u = __float_as_uint(f);
  return (ushort)((u + 0x7FFFu + ((u >> 16) & 1u)) >> 16);
}
__device__ inline void unp(uint u, float& lo, float& hi) {  // packed bf16 -> fp32
  lo = __uint_as_float(u << 16);
  hi = __uint_as_float(u & 0xFFFF0000u);
}
// ushort index into a [px][256B] LDS buffer, T2 XOR-swizzled (involution).
__device__ inline int swz16(int px, int byte) {
  return (px * 256 + (byte ^ ((px & 7) << 4))) >> 1;
}

// ------- kernel 0a: x [B][C][HW] fp32 -> xt [B][HW][C] bf16 -----------------
__global__ __launch_bounds__(256) void k_xt(const float* __restrict__ x,
                                            ushort* __restrict__ xt) {
  const int t = threadIdx.x;
  const int g = t >> 4;            // channel chunk: c = 8g..8g+7
  const int hl = t & 15;
  const int p0 = blockIdx.x * 16;
  const int b = p0 / HW, hw = p0 - b * HW + hl;
  const float* xb = x + (size_t)b * C * HW + hw;
  uint u[4];
#pragma unroll
  for (int i = 0; i < 4; ++i) {
    float lo = xb[(size_t)(g * 8 + 2 * i) * HW];
    float hi = xb[(size_t)(g * 8 + 2 * i + 1) * HW];
    u[i] = (uint)f2b(lo) | ((uint)f2b(hi) << 16);
  }
  *(uint4*)(xt + ((size_t)b * HW + hw) * C + g * 8) = make_uint4(u[0], u[1], u[2], u[3]);
}

// ------- kernel 0b: weight transforms (both convs), k-major bf16 ------------
// wt [O][k*128+c] = w_dcn[o][c][k];  wof [32][k*128+c] = o<27 ? w_off[o][c][k] : 0
__global__ __launch_bounds__(256) void k_wt2(const float* __restrict__ w_dcn,
                                             const float* __restrict__ w_off,
                                             ushort* __restrict__ wt,
                                             ushort* __restrict__ wof) {
  int i = blockIdx.x * 256 + threadIdx.x;
  if (i < O * KC) {
    int c = i & 127, k = (i >> 7) % 9, o = i / KC;
    wt[i] = f2b(w_dcn[(size_t)o * KC + c * 9 + k]);
  }
  if (i < 32 * KC) {
    int c = i & 127, k = (i >> 7) % 9, o = i / KC;
    wof[i] = (o < 27) ? f2b(w_off[((size_t)o * C + c) * 9 + k]) : (ushort)0;
  }
}

// ------- kernel 1: offset conv via MFMA (C=128 -> 27, 3x3, pad 1) -----------
// block: 256 thr (4 waves), 64 px, M=32 (27 used), per-tap K=128, dbuf LDS.
__global__ __launch_bounds__(256, 4) void k_offc3(
    const ushort* __restrict__ xt, const ushort* __restrict__ wof,
    const float* __restrict__ b_off, float* __restrict__ om) {
  __shared__ __align__(16) ushort s_buf[2][PX * 128];
  const int t = threadIdx.x;
  const int bid = (blockIdx.x & 7) * 100 + (blockIdx.x >> 3);  // XCD chunking
  const int b = bid / 100, hw0 = (bid % 100) * PX;
  const int spx = t >> 2, sj = t & 3;
  const int hwp = hw0 + spx, hp = hwp / W, wp = hwp - hp * W;
  const ushort* xb = xt + (size_t)b * HW * C;
  uint4 ld[4];

  auto SLOAD = [&](int k) {
    int ky = k / 3, kx = k - ky * 3;
    int y = hp + ky - 1, xx = wp + kx - 1;
    bool ok = ((unsigned)y < (unsigned)H) && ((unsigned)xx < (unsigned)W);
    const ushort* r = xb + (size_t)(y * W + xx) * C + sj * 8;
#pragma unroll
    for (int e = 0; e < 4; ++e)
      ld[e] = ok ? *(const uint4*)(r + e * 32) : make_uint4(0u, 0u, 0u, 0u);
  };
  auto SWRITE = [&](ushort* buf) {
#pragma unroll
    for (int e = 0; e < 4; ++e)
      *(uint4*)(buf + swz16(spx, e * 64 + sj * 16)) = ld[e];
  };

  const int lane = t & 63, wv = t >> 6, rl = lane & 15, gh = lane >> 4;
  f32x4 acc[2] = {{0.f, 0.f, 0.f, 0.f}, {0.f, 0.f, 0.f, 0.f}};
  auto COMP = [&](const ushort* buf, int k) {
    const ushort* a0 = wof + (size_t)rl * KC + k * 128 + gh * 8;
#pragma unroll
    for (int kk = 0; kk < 128; kk += 32) {
      short8 av0 = *(const short8*)(a0 + kk);
      short8 av1 = *(const short8*)(a0 + 16 * KC + kk);
      short8 bv = *(const short8*)(buf + swz16(wv * 16 + rl, kk * 2 + gh * 16));
      acc[0] = __builtin_amdgcn_mfma_f32_16x16x32_bf16(av0, bv, acc[0], 0, 0, 0);
      acc[1] = __builtin_amdgcn_mfma_f32_16x16x32_bf16(av1, bv, acc[1], 0, 0, 0);
    }
  };

  SLOAD(0); SWRITE(s_buf[0]); __syncthreads();
  for (int k = 0; k < 9; ++k) {
    if (k < 8) SLOAD(k + 1);
    COMP(s_buf[k & 1], k);
    if (k < 8) { SWRITE(s_buf[(k + 1) & 1]); __syncthreads(); }
  }
  // D: col(px-in-tile)=lane&15, row(o)=16m+4gh+r; wave wv owns px 16wv..+16
  float* ob = om + (size_t)b * 27 * HW + hw0 + wv * 16 + rl;
#pragma unroll
  for (int m = 0; m < 2; ++m)
#pragma unroll
    for (int r = 0; r < 4; ++r) {
      int oc = m * 16 + gh * 4 + r;
      if (oc < 27) ob[(size_t)oc * HW] = acc[m][r] + b_off[oc];
    }
}

// ------- kernel 2: bilinear gather + MFMA GEMM, 64 px/block, dbuf ----------
__global__ __launch_bounds__(256, 3) void k_dcn3(
    const ushort* __restrict__ xt, const float* __restrict__ om,
    const ushort* __restrict__ wt, float* __restrict__ outr) {
  __shared__ float s_w[PX][9][4];
  __shared__ int s_i[PX][9][4];
  __shared__ __align__(16) ushort s_buf[2][PX * 128];
  const int t = threadIdx.x;
  const int bid = (blockIdx.x & 7) * 100 + (blockIdx.x >> 3);  // XCD chunking
  const int b = bid / 100, hw0 = (bid % 100) * PX;

  // metadata: 64 px x 9 taps (mask folded into corner weights)
  for (int idx = t; idx < PX * 9; idx += 256) {
    int px = idx / 9, k = idx - (idx / 9) * 9;
    int hw = hw0 + px, h = hw / W, w = hw - (hw / W) * W;
    int ky = k / 3, kx = k - ky * 3;
    const float* omp = om + (size_t)b * 27 * HW + hw;
    float dy = omp[(size_t)(2 * k) * HW];
    float dx = omp[(size_t)(2 * k + 1) * HW];
    float mk = 1.0f / (1.0f + __expf(-omp[(size_t)(18 + k) * HW]));
    float py = dy + (float)(h - 1 + ky);
    float pxf = dx + (float)(w - 1 + kx);
    float y0f = floorf(py), x0f = floorf(pxf);
    float wy1 = py - y0f, wx1 = pxf - x0f;
    float wy0 = 1.0f - wy1, wx0 = 1.0f - wx1;
    int y0 = (int)y0f, x0 = (int)x0f;
    int y1 = y0 + 1, x1 = x0 + 1;
    bool vy0 = (y0 >= 0) && (y0 < H);
    bool vy1 = (y1 >= 0) && (y1 < H);
    bool vx0 = (x0 >= 0) && (x0 < W);
    bool vx1 = (x1 >= 0) && (x1 < W);
    int cy0 = min(max(y0, 0), H - 1), cy1 = min(max(y1, 0), H - 1);
    int cx0 = min(max(x0, 0), W - 1), cx1 = min(max(x1, 0), W - 1);
    s_w[px][k][0] = (vy0 && vx0) ? wy0 * wx0 * mk : 0.0f;
    s_w[px][k][1] = (vy0 && vx1) ? wy0 * wx1 * mk : 0.0f;
    s_w[px][k][2] = (vy1 && vx0) ? wy1 * wx0 * mk : 0.0f;
    s_w[px][k][3] = (vy1 && vx1) ? wy1 * wx1 * mk : 0.0f;
    s_i[px][k][0] = cy0 * W + cx0;
    s_i[px][k][1] = cy0 * W + cx1;
    s_i[px][k][2] = cy1 * W + cx0;
    s_i[px][k][3] = cy1 * W + cx1;
  }
  __syncthreads();

  const int spx = t >> 2, sj = t & 3;
  const ushort* xb = xt + (size_t)b * HW * C + sj * 8;
  uint4 ld[4][4];   // [corner][e] — all indices compile-time (rule #20)
  float cw0, cw1, cw2, cw3;

  auto SLOAD = [&](int k) {
    int4 ii = *(const int4*)&s_i[spx][k][0];
    float4 wwv = *(const float4*)&s_w[spx][k][0];
    cw0 = wwv.x; cw1 = wwv.y; cw2 = wwv.z; cw3 = wwv.w;
    const ushort* r0 = xb + (size_t)ii.x * C;
    const ushort* r1 = xb + (size_t)ii.y * C;
    const ushort* r2 = xb + (size_t)ii.z * C;
    const ushort* r3 = xb + (size_t)ii.w * C;
#pragma unroll
    for (int e = 0; e < 4; ++e) {
      ld[0][e] = *(const uint4*)(r0 + e * 32);
      ld[1][e] = *(const uint4*)(r1 + e * 32);
      ld[2][e] = *(const uint4*)(r2 + e * 32);
      ld[3][e] = *(const uint4*)(r3 + e * 32);
    }
  };
  auto SWRITE = [&](ushort* buf) {
#pragma unroll
    for (int e = 0; e < 4; ++e) {
      uint q0[4] = {ld[0][e].x, ld[0][e].y, ld[0][e].z, ld[0][e].w};
      uint q1[4] = {ld[1][e].x, ld[1][e].y, ld[1][e].z, ld[1][e].w};
      uint q2[4] = {ld[2][e].x, ld[2][e].y, ld[2][e].z, ld[2][e].w};
      uint q3[4] = {ld[3][e].x, ld[3][e].y, ld[3][e].z, ld[3][e].w};
      uint r[4];
#pragma unroll
      for (int d = 0; d < 4; ++d) {
        float a0, a1, b0, b1, c0, c1, d0, d1;
        unp(q0[d], a0, a1);
        unp(q1[d], b0, b1);
        unp(q2[d], c0, c1);
        unp(q3[d], d0, d1);
        float vlo = fmaf(cw3, d0, fmaf(cw2, c0, fmaf(cw1, b0, cw0 * a0)));
        float vhi = fmaf(cw3, d1, fmaf(cw2, c1, fmaf(cw1, b1, cw0 * a1)));
        r[d] = (uint)f2b(vlo) | ((uint)f2b(vhi) << 16);
      }
      *(uint4*)(buf + swz16(spx, e * 64 + sj * 16)) = make_uint4(r[0], r[1], r[2], r[3]);
    }
  };

  const int lane = t & 63, wv = t >> 6, rl = lane & 15, gh = lane >> 4;
  f32x4 acc[2][4];
#pragma unroll
  for (int m = 0; m < 2; ++m)
#pragma unroll
    for (int nt = 0; nt < 4; ++nt) acc[m][nt] = {0.f, 0.f, 0.f, 0.f};

  auto COMP = [&](const ushort* buf, int k) {
    const ushort* a0 = wt + (size_t)(wv * 32 + rl) * KC + k * 128 + gh * 8;
    __builtin_amdgcn_s_setprio(1);
#pragma unroll
    for (int kk = 0; kk < 128; kk += 32) {
      short8 av0 = *(const short8*)(a0 + kk);
      short8 av1 = *(const short8*)(a0 + 16 * KC + kk);
#pragma unroll
      for (int nt = 0; nt < 4; ++nt) {
        short8 bv = *(const short8*)(buf + swz16(nt * 16 + rl, kk * 2 + gh * 16));
        acc[0][nt] = __builtin_amdgcn_mfma_f32_16x16x32_bf16(av0, bv, acc[0][nt], 0, 0, 0);
        acc[1][nt] = __builtin_amdgcn_mfma_f32_16x16x32_bf16(av1, bv, acc[1][nt], 0, 0, 0);
      }
    }
    __builtin_amdgcn_s_setprio(0);
  };

  SLOAD(0); SWRITE(s_buf[0]); __syncthreads();
  for (int k = 0; k < 9; ++k) {
    if (k < 8) SLOAD(k + 1);
    COMP(s_buf[k & 1], k);
    if (k < 8) { SWRITE(s_buf[(k + 1) & 1]); __syncthreads(); }
  }
  // D: col(px)=lane&15 within n-tile, row(o)=32wv+16m+4gh+r
  float* outb = outr + (size_t)b * O * HW + hw0 + rl;
#pragma unroll
  for (int m = 0; m < 2; ++m)
#pragma unroll
    for (int nt = 0; nt < 4; ++nt)
#pragma unroll
      for (int r = 0; r < 4; ++r)
        outb[(size_t)(wv * 32 + m * 16 + gh * 4 + r) * HW + nt * 16] = acc[m][nt][r];
}

// ------- kernel 3: BN partial sums (512 blocks = 4 per channel) -------------
__global__ __launch_bounds__(256) void k_bnstats2(const float* __restrict__ outr,
                                                  float* __restrict__ part) {
  const int o = blockIdx.x >> 2, pb = blockIdx.x & 3;   // batches 2pb..2pb+1
  float s = 0.f, s2 = 0.f;
  for (int i = threadIdx.x; i < 2 * HW / 4; i += 256) {
    int bb = i / (HW / 4);
    float4 v = ((const float4*)(outr + ((size_t)(2 * pb + bb) * O + o) * HW))[i - bb * (HW / 4)];
    s += v.x + v.y + v.z + v.w;
    s2 = fmaf(v.x, v.x, s2);
    s2 = fmaf(v.y, v.y, s2);
    s2 = fmaf(v.z, v.z, s2);
    s2 = fmaf(v.w, v.w, s2);
  }
#pragma unroll
  for (int off = 32; off > 0; off >>= 1) {
    s += __shfl_down(s, off);
    s2 += __shfl_down(s2, off);
  }
  __shared__ float rs[4], rs2[4];
  int wid = threadIdx.x >> 6, lane = threadIdx.x & 63;
  if (lane == 0) { rs[wid] = s; rs2[wid] = s2; }
  __syncthreads();
  if (threadIdx.x == 0) {
    float S = rs[0] + rs[1] + rs[2] + rs[3];
    float S2 = rs2[0] + rs2[1] + rs2[2] + rs2[3];
    part[(o * 4 + pb) * 2] = S;
    part[(o * 4 + pb) * 2 + 1] = S2;
  }
}

// ------- kernel 4: BN finalize + affine + SiLU, in place on d_out -----------
__global__ __launch_bounds__(256) void k_bnapply2(
    float* __restrict__ outr, const float* __restrict__ part,
    const float* __restrict__ gamma, const float* __restrict__ beta) {
  const int n4 = B * O * HW / 4;
  for (int i = blockIdx.x * blockDim.x + threadIdx.x; i < n4;
       i += gridDim.x * blockDim.x) {
    int o = (i / (HW / 4)) % O;
    float S = 0.f, S2 = 0.f;
#pragma unroll
    for (int pb = 0; pb < 4; ++pb) {
      S += part[(o * 4 + pb) * 2];
      S2 += part[(o * 4 + pb) * 2 + 1];
    }
    const float inv = 1.0f / (float)(B * HW);
    float mu = S * inv;
    float rstd = rsqrtf(fmaf(S2, inv, -mu * mu) + 1e-5f);
    float a = rstd * gamma[o];
    float bb = fmaf(-mu, a, beta[o]);
    float4 v = ((const float4*)outr)[i];
    float y0 = fmaf(v.x, a, bb);
    float y1 = fmaf(v.y, a, bb);
    float y2 = fmaf(v.z, a, bb);
    float y3 = fmaf(v.w, a, bb);
    v.x = y0 / (1.0f + __expf(-y0));
    v.y = y1 / (1.0f + __expf(-y1));
    v.z = y2 / (1.0f + __expf(-y2));
    v.w = y3 / (1.0f + __expf(-y3));
    ((float4*)outr)[i] = v;
  }
}

extern "C" void kernel_launch(void* const* d_in, const int* in_sizes, int n_in,
                              void* d_out, int out_size, void* d_ws, size_t ws_size,
                              hipStream_t stream) {
  const float* x = (const float*)d_in[0];
  const float* w_dcn = (const float*)d_in[1];
  // d_in[2] = b_dcn: per-channel constant, exactly cancelled by BN mean-sub.
  const float* w_off = (const float*)d_in[3];
  const float* b_off = (const float*)d_in[4];
  const float* gamma = (const float*)d_in[5];
  const float* beta = (const float*)d_in[6];
  float* out = (float*)d_out;
  // ws layout: om 5.53MB | xt 13.1MB | wt 288KB | wof 72KB | part 4KB (~19MB)
  float* om = (float*)d_ws;
  ushort* xt = (ushort*)(om + (size_t)B * 27 * HW);
  ushort* wt = xt + (size_t)B * HW * C;
  ushort* wof = wt + (size_t)O * KC;
  float* part = (float*)(wof + (size_t)32 * KC);

  k_xt<<<NPIX / 16, 256, 0, stream>>>(x, xt);
  k_wt2<<<(O * KC + 255) / 256, 256, 0, stream>>>(w_dcn, w_off, wt, wof);
  k_offc3<<<NPIX / PX, 256, 0, stream>>>(xt, wof, b_off, om);
  k_dcn3<<<NPIX / PX, 256, 0, stream>>>(xt, om, wt, out);
  k_bnstats2<<<O * 4, 256, 0, stream>>>(out, part);
  k_bnapply2<<<2048, 256, 0, stream>>>(out, part, gamma, beta);
}